// Round 10
// baseline (5462.943 us; speedup 1.0000x reference)
//
#include <hip/hip_runtime.h>
#include <math.h>

#define H 200
#define TT 4
#define BB 64
#define MM 1000
#define NEGV (-1e30f)

static const int ROWS = BB * MM;   // 64000
#define KA 416                     // 400 padded to x32
#define KB 224                     // 200 padded to x32
#define NPAD 896                   // 800 padded to 7*128
#define NSLICE 28                  // fallback partial slices
#define LSTR 40                    // fallback kernel LDS row stride (ushorts)
#define RP 500                     // row panels
#define GG 3528                    // 63 groups * 56 (8 rp x 7 np), rp>=500 guarded

typedef __attribute__((ext_vector_type(8))) short short8;
typedef __attribute__((ext_vector_type(4))) float f32x4;

__device__ __forceinline__ void split2(float x, unsigned short& h, unsigned short& l) {
  unsigned u = __float_as_uint(x);
  h = (unsigned short)(u >> 16);
  float res = x - __uint_as_float(u & 0xffff0000u);
  l = (unsigned short)(__float_as_uint(res) >> 16);
}
__device__ __forceinline__ float bf2f(unsigned short h) {
  return __uint_as_float(((unsigned)h) << 16);
}
__device__ __forceinline__ void gload16(const unsigned short* g, const unsigned short* l) {
  __builtin_amdgcn_global_load_lds(
      (const __attribute__((address_space(1))) void*)g,
      (__attribute__((address_space(3))) void*)l, 16, 0, 0);
}

// ---------------------------------------------------------------- init
__global__ __launch_bounds__(256) void k_init(const int* __restrict__ dmask,
    int* st_s, int* st_e, int* ms, int* me,
    float* h, float* c, float* out) {
  int b = blockIdx.x, t = threadIdx.x;
  __shared__ int red[256];
  int sum = 0;
  for (int m = t; m < MM; m += 256) sum += dmask[b * MM + m];
  red[t] = sum; __syncthreads();
  for (int s = 128; s > 0; s >>= 1) { if (t < s) red[t] += red[t + s]; __syncthreads(); }
  if (t == 0) { st_s[b] = 0; st_e[b] = red[0] - 1; ms[b] = 1; me[b] = 1; }
  for (int i = t; i < H; i += 256) { h[b * H + i] = 0.f; c[b * H + i] = 0.f; }
  if (b == 0 && t == 0) out[0] = 0.f;
}

// ---------------------------------------------------------------- transpose: dst[k][r]=src[r][koff+k]
__global__ __launch_bounds__(256) void k_T(const float* __restrict__ src, int ld,
    int R, int koff, float* __restrict__ dst) {
  int k = blockIdx.x;
  for (int r = threadIdx.x; r < R; r += 256)
    dst[(size_t)k * R + r] = src[(size_t)r * ld + koff + k];
}

// ---------------------------------------------------------------- split -> swizzled panel format
__global__ __launch_bounds__(256) void k_splitP(const float* __restrict__ src, int srcld,
    int Ksrc, int Nsrc,
    unsigned short* __restrict__ hi, unsigned short* __restrict__ lo, int Kpad) {
  int r = blockIdx.x;
  int r7 = r & 127;
  size_t pbase = (size_t)(r >> 7) * (size_t)(128 * Kpad);
  int sw = (r7 >> 1) & 3;
  for (int k = threadIdx.x; k < Kpad; k += 256) {
    unsigned short h = 0, l = 0;
    if (r < Nsrc && k < Ksrc) split2(src[(size_t)r * srcld + k], h, l);
    size_t addr = pbase + (size_t)(k >> 5) * 4096 + r7 * 32 +
                  ((((k >> 3) & 3) ^ sw) << 3) + (k & 7);
    hi[addr] = h; lo[addr] = l;
  }
}

// W1 split with output-neuron permutation within 64-row groups
__global__ __launch_bounds__(256) void k_splitPW1(const float* __restrict__ src,
    unsigned short* __restrict__ hi, unsigned short* __restrict__ lo) {
  int r = blockIdx.x;
  int o = (r & ~63) + ((r & 15) << 2) + ((r >> 4) & 3);
  int r7 = r & 127;
  size_t pbase = (size_t)(r >> 7) * (size_t)(128 * KA);
  int sw = (r7 >> 1) & 3;
  for (int k = threadIdx.x; k < KA; k += 256) {
    unsigned short h = 0, l = 0;
    if (o < 800 && k < 400) split2(src[(size_t)o * 600 + k], h, l);
    size_t addr = pbase + (size_t)(k >> 5) * 4096 + r7 * 32 +
                  ((((k >> 3) & 3) ^ sw) << 3) + (k & 7);
    hi[addr] = h; lo[addr] = l;
  }
}

// ---------------------------------------------------------------- row-major weight split (fallback)
__global__ __launch_bounds__(256) void k_split(const float* __restrict__ src, int srcld,
    int Ksrc, int Nsrc,
    unsigned short* __restrict__ hi, unsigned short* __restrict__ lo, int Kpad) {
  int r = blockIdx.x;
  for (int k = threadIdx.x; k < Kpad; k += 256) {
    unsigned short h = 0, l = 0;
    if (r < Nsrc && k < Ksrc) split2(src[(size_t)r * srcld + k], h, l);
    hi[(size_t)r * Kpad + k] = h;
    lo[(size_t)r * Kpad + k] = l;
  }
}

// ================= split-K multi-block decoder chain =================
__global__ __launch_bounds__(256) void k_prep(const float* __restrict__ U,
    const int* __restrict__ st_s, const int* __restrict__ st_e,
    float* __restrict__ ucat, float* __restrict__ ue) {
  int b = blockIdx.x, t = threadIdx.x;
  int si = st_s[b], ei = st_e[b];
  const float* Us = U + ((size_t)b * MM + si) * 400;
  const float* Ue = U + ((size_t)b * MM + ei) * 400;
  for (int i = t; i < 400; i += 256) {
    float uv = Ue[i];
    ucat[b * 800 + i] = Us[i];
    ucat[b * 800 + 400 + i] = uv;
    ue[b * 400 + i] = uv;
  }
}

__global__ __launch_bounds__(256) void k_gates(
    const float* __restrict__ ucat, const float* __restrict__ hbuf,
    const float* __restrict__ wTih, const float* __restrict__ wThh,
    const float* __restrict__ b_ih, const float* __restrict__ b_hh,
    float* __restrict__ g) {
  const int b = blockIdx.y, t = threadIdx.x;
  const int o = blockIdx.x * 64 + (t & 63);
  const int oc = o < 800 ? o : 799;
  const int ks = t >> 6;
  __shared__ float xs[800], hs[200], red[256];
  for (int i = t; i < 800; i += 256) xs[i] = ucat[b * 800 + i];
  for (int i = t; i < 200; i += 256) hs[i] = hbuf[b * H + i];
  __syncthreads();
  float acc = 0.f;
#pragma unroll 8
  for (int k = ks * 200; k < ks * 200 + 200; ++k)
    acc = fmaf(wTih[(size_t)k * 800 + oc], xs[k], acc);
#pragma unroll 8
  for (int k = ks * 50; k < ks * 50 + 50; ++k)
    acc = fmaf(wThh[(size_t)k * 800 + oc], hs[k], acc);
  red[t] = acc; __syncthreads();
  if (ks == 0 && o < 800)
    g[b * 800 + o] = red[t] + red[t + 64] + red[t + 128] + red[t + 192] + b_ih[o] + b_hh[o];
}

__global__ __launch_bounds__(256) void k_act(const float* __restrict__ g,
    float* __restrict__ h, float* __restrict__ c) {
  int b = blockIdx.x, t = threadIdx.x;
  if (t >= H) return;
  float ig = 1.f / (1.f + expf(-g[b * 800 + t]));
  float fg = 1.f / (1.f + expf(-g[b * 800 + 200 + t]));
  float gg = tanhf(g[b * 800 + 400 + t]);
  float og = 1.f / (1.f + expf(-g[b * 800 + 600 + t]));
  float cn = fg * c[b * H + t] + ig * gg;
  c[b * H + t] = cn;
  h[b * H + t] = og * tanhf(cn);
}

template <int TAG>
__global__ __launch_bounds__(256) void k_r2(
    const float* __restrict__ U, const int* __restrict__ st_s,
    const float* __restrict__ ucat, const float* __restrict__ ue,
    const float* __restrict__ hbuf, const float* __restrict__ WrT,
    float* __restrict__ rbuf) {
  const int b = blockIdx.y, t = threadIdx.x;
  const int o = blockIdx.x * 64 + (t & 63);
  const int oc = o < 200 ? o : 199;
  const int ks = t >> 6;
  __shared__ float xcs[1000], red[256];
  for (int i = t; i < 200; i += 256) xcs[i] = hbuf[b * H + i];
  if (TAG == 0) {
    for (int i = t; i < 800; i += 256) xcs[200 + i] = ucat[b * 800 + i];
  } else {
    const float* Us = U + ((size_t)b * MM + st_s[b]) * 400;
    for (int i = t; i < 400; i += 256) {
      xcs[200 + i] = Us[i];
      xcs[600 + i] = ue[b * 400 + i];
    }
  }
  __syncthreads();
  float acc = 0.f;
#pragma unroll 8
  for (int k = ks * 250; k < ks * 250 + 250; ++k)
    acc = fmaf(WrT[(size_t)k * 200 + oc], xcs[k], acc);
  red[t] = acc; __syncthreads();
  if (ks == 0 && o < 200)
    rbuf[b * 200 + o] = tanhf(red[t] + red[t + 64] + red[t + 128] + red[t + 192]);
}

__global__ __launch_bounds__(256) void k_rcorr(
    const float* __restrict__ rbuf, const float* __restrict__ W1cT,
    const float* __restrict__ b1, float* __restrict__ rcorr) {
  const int b = blockIdx.y, t = threadIdx.x;
  const int o = blockIdx.x * 64 + (t & 63);
  const int oc = o < 800 ? o : 799;
  const int ks = t >> 6;
  __shared__ float rs[200], red[256];
  for (int i = t; i < 200; i += 256) rs[i] = rbuf[b * 200 + i];
  __syncthreads();
  float acc = 0.f;
#pragma unroll 8
  for (int k = ks * 50; k < ks * 50 + 50; ++k)
    acc = fmaf(W1cT[(size_t)k * 800 + oc], rs[k], acc);
  red[t] = acc; __syncthreads();
  if (ks == 0)
    rcorr[b * NPAD + o] = (o < 800)
        ? red[t] + red[t + 64] + red[t + 128] + red[t + 192] + b1[o] : 0.f;
}

// ================= fallback chain kernels (ws too small) =================
__global__ __launch_bounds__(1024) void k_lstm_r(
    const float* __restrict__ U, const int* __restrict__ st_s, const int* __restrict__ st_e,
    float* __restrict__ h, float* __restrict__ c,
    const float* __restrict__ w_ih, const float* __restrict__ w_hh,
    const float* __restrict__ b_ih, const float* __restrict__ b_hh,
    const float* __restrict__ Wr, const float* __restrict__ W1, const float* __restrict__ b1,
    float* __restrict__ rcorr, float* __restrict__ ue) {
  int b = blockIdx.x, t = threadIdx.x;
  __shared__ float xc[1000];
  __shared__ float hold[H];
  __shared__ float g[800];
  __shared__ float r[H];
  int si = st_s[b], ei = st_e[b];
  const float* Us = U + ((size_t)b * MM + si) * 400;
  const float* Ue = U + ((size_t)b * MM + ei) * 400;
  if (t < 400) { xc[200 + t] = Us[t]; xc[600 + t] = Ue[t]; ue[b * 400 + t] = Ue[t]; }
  if (t >= 400 && t < 600) hold[t - 400] = h[b * H + (t - 400)];
  __syncthreads();
  if (t < 800) {
    float acc = b_ih[t] + b_hh[t];
    const float4* wi = (const float4*)(w_ih + (size_t)t * 800);
    const float* xv = &xc[200];
    for (int k = 0; k < 200; ++k) {
      float4 wv = wi[k];
      acc = fmaf(wv.x, xv[k * 4 + 0], acc); acc = fmaf(wv.y, xv[k * 4 + 1], acc);
      acc = fmaf(wv.z, xv[k * 4 + 2], acc); acc = fmaf(wv.w, xv[k * 4 + 3], acc);
    }
    const float4* wh = (const float4*)(w_hh + (size_t)t * H);
    for (int k = 0; k < 50; ++k) {
      float4 wv = wh[k];
      acc = fmaf(wv.x, hold[k * 4 + 0], acc); acc = fmaf(wv.y, hold[k * 4 + 1], acc);
      acc = fmaf(wv.z, hold[k * 4 + 2], acc); acc = fmaf(wv.w, hold[k * 4 + 3], acc);
    }
    g[t] = acc;
  }
  __syncthreads();
  if (t < H) {
    float ig = 1.f / (1.f + expf(-g[t]));
    float fg = 1.f / (1.f + expf(-g[H + t]));
    float gg = tanhf(g[2 * H + t]);
    float og = 1.f / (1.f + expf(-g[3 * H + t]));
    float cn = fg * c[b * H + t] + ig * gg;
    c[b * H + t] = cn;
    float hv = og * tanhf(cn);
    h[b * H + t] = hv;
    xc[t] = hv;
  }
  __syncthreads();
  if (t < H) {
    float acc = 0.f;
    const float4* wr = (const float4*)(Wr + (size_t)t * 1000);
    for (int k = 0; k < 250; ++k) {
      float4 wv = wr[k];
      acc = fmaf(wv.x, xc[k * 4 + 0], acc); acc = fmaf(wv.y, xc[k * 4 + 1], acc);
      acc = fmaf(wv.z, xc[k * 4 + 2], acc); acc = fmaf(wv.w, xc[k * 4 + 3], acc);
    }
    r[t] = tanhf(acc);
  }
  __syncthreads();
  if (t < NPAD) {
    float acc = 0.f;
    if (t < 800) {
      acc = b1[t];
      const float4* w1 = (const float4*)(W1 + (size_t)t * 600 + 400);
      for (int k = 0; k < 50; ++k) {
        float4 wv = w1[k];
        acc = fmaf(wv.x, r[k * 4 + 0], acc); acc = fmaf(wv.y, r[k * 4 + 1], acc);
        acc = fmaf(wv.z, r[k * 4 + 2], acc); acc = fmaf(wv.w, r[k * 4 + 3], acc);
      }
    }
    rcorr[b * NPAD + t] = acc;
  }
}

__global__ __launch_bounds__(1024) void k_re(
    const float* __restrict__ U, const int* __restrict__ st_s,
    const float* __restrict__ ue, const float* __restrict__ h,
    const float* __restrict__ Wr, const float* __restrict__ W1, const float* __restrict__ b1,
    float* __restrict__ rcorr) {
  int b = blockIdx.x, t = threadIdx.x;
  __shared__ float xc[1000];
  __shared__ float r[H];
  const float* Us = U + ((size_t)b * MM + st_s[b]) * 400;
  if (t < 200) xc[t] = h[b * H + t];
  if (t >= 200 && t < 600) xc[t] = Us[t - 200];
  if (t >= 600 && t < 1000) xc[t] = ue[b * 400 + (t - 600)];
  __syncthreads();
  if (t < H) {
    float acc = 0.f;
    const float4* wr = (const float4*)(Wr + (size_t)t * 1000);
    for (int k = 0; k < 250; ++k) {
      float4 wv = wr[k];
      acc = fmaf(wv.x, xc[k * 4 + 0], acc); acc = fmaf(wv.y, xc[k * 4 + 1], acc);
      acc = fmaf(wv.z, xc[k * 4 + 2], acc); acc = fmaf(wv.w, xc[k * 4 + 3], acc);
    }
    r[t] = tanhf(acc);
  }
  __syncthreads();
  if (t < NPAD) {
    float acc = 0.f;
    if (t < 800) {
      acc = b1[t];
      const float4* w1 = (const float4*)(W1 + (size_t)t * 600 + 400);
      for (int k = 0; k < 50; ++k) {
        float4 wv = w1[k];
        acc = fmaf(wv.x, r[k * 4 + 0], acc); acc = fmaf(wv.y, r[k * 4 + 1], acc);
        acc = fmaf(wv.z, r[k * 4 + 2], acc); acc = fmaf(wv.w, r[k * 4 + 3], acc);
      }
    }
    rcorr[b * NPAD + t] = acc;
  }
}

// ---------------------------------------------------------------- panel MFMA GEMM
// A and B both single-buffered via gload_lds; fragments lifted to regs between
// barrier1/barrier2, next-tile DMA issued after barrier2 -> 32KB LDS, 5 blocks/CU.
// MODE 0: permuted W1 -> in-register maxpool, write m1 panels. No partials.
// MODE 1: W2 -> shfl pooling + alpha slices 0..13 (stride 14).
template <int MODE>
__global__ __launch_bounds__(256, 5) void k_pgemm(
    const unsigned short* __restrict__ Ah, const unsigned short* __restrict__ Al,
    const unsigned short* __restrict__ Bh, const unsigned short* __restrict__ Bl,
    const float* __restrict__ addv,
    unsigned short* __restrict__ Couth, unsigned short* __restrict__ Coutl,
    float* __restrict__ partial, const float* __restrict__ W12) {
  const int Kpad = (MODE == 0) ? KA : KB;
  const int nk = Kpad >> 5;
  __shared__ unsigned short sA[8192];   // [hi 4096 | lo 4096]
  __shared__ unsigned short sB[8192];
  const int id = blockIdx.x;
  const int g = id / 56, rem = id % 56;
  const int np = rem >> 3, c8 = rem & 7;
  const int rp = g * 8 + c8;
  if (rp >= RP) return;
  const int tid = threadIdx.x;
  const int lane = tid & 63, wave = tid >> 6;
  const int wm = wave >> 1, wn = wave & 1;
  const int row0 = rp * 128, n0 = np * 128;
  const int lr = lane & 15, ls = lane >> 4;
  const size_t panelA = (size_t)rp * (size_t)(128 * Kpad);
  const size_t panelB = (size_t)np * (size_t)(128 * Kpad);
  const int aoff = (wm * 64 + lr) * 32 + ((ls ^ ((lr >> 1) & 3)) << 3);
  const int boff = (wn * 64 + lr) * 32 + ((ls ^ ((lr >> 1) & 3)) << 3);

  f32x4 acc[4][4];
#pragma unroll
  for (int i = 0; i < 4; ++i)
#pragma unroll
    for (int j = 0; j < 4; ++j) acc[i][j] = (f32x4){0.f, 0.f, 0.f, 0.f};

  auto issueA = [&](int kt) {
    const size_t tA = panelA + (size_t)kt * 4096;
#pragma unroll
    for (int q = 0; q < 2; ++q) {
      const int cc = (q * 4 + wave) * 512;
      gload16(Ah + tA + cc + lane * 8, &sA[cc]);
      gload16(Al + tA + cc + lane * 8, &sA[4096 + cc]);
    }
  };
  auto issueB = [&](int kt) {
    const size_t tB = panelB + (size_t)kt * 4096;
#pragma unroll
    for (int q = 0; q < 2; ++q) {
      const int cc = (q * 4 + wave) * 512;
      gload16(Bh + tB + cc + lane * 8, &sB[cc]);
      gload16(Bl + tB + cc + lane * 8, &sB[4096 + cc]);
    }
  };

  issueA(0);
  issueB(0);
  for (int kt = 0; kt < nk; ++kt) {
    __syncthreads();                       // barrier1: this tile's DMAs complete
    short8 bh[4], bl[4], fah[4], fal[4];
#pragma unroll
    for (int j = 0; j < 4; ++j) {
      bh[j] = *(const short8*)(sB + boff + j * 512);
      bl[j] = *(const short8*)(sB + 4096 + boff + j * 512);
    }
#pragma unroll
    for (int i = 0; i < 4; ++i) {
      fah[i] = *(const short8*)(sA + aoff + i * 512);
      fal[i] = *(const short8*)(sA + 4096 + aoff + i * 512);
    }
    __syncthreads();                       // barrier2: all waves done reading LDS
    if (kt + 1 < nk) { issueA(kt + 1); issueB(kt + 1); }  // overwrite under MFMA
#pragma unroll
    for (int i = 0; i < 4; ++i)
#pragma unroll
      for (int j = 0; j < 4; ++j)
        acc[i][j] = __builtin_amdgcn_mfma_f32_16x16x32_bf16(fah[i], bh[j], acc[i][j], 0, 0, 0);
#pragma unroll
    for (int i = 0; i < 4; ++i)
#pragma unroll
      for (int j = 0; j < 4; ++j)
        acc[i][j] = __builtin_amdgcn_mfma_f32_16x16x32_bf16(fah[i], bl[j], acc[i][j], 0, 0, 0);
#pragma unroll
    for (int i = 0; i < 4; ++i)
#pragma unroll
      for (int j = 0; j < 4; ++j)
        acc[i][j] = __builtin_amdgcn_mfma_f32_16x16x32_bf16(fal[i], bh[j], acc[i][j], 0, 0, 0);
  }

  if (MODE == 0) {
    const int obase = n0 + wn * 64 + lr * 4;
    const int po = ((n0 + wn * 64) >> 2) + lr;
    const unsigned b0 = (unsigned)row0 / 1000u;
    const unsigned b1 = (unsigned)(row0 + 127) / 1000u;
    float rc0[4], rc1[4];
#pragma unroll
    for (int j = 0; j < 4; ++j) {
      rc0[j] = addv[b0 * NPAD + obase + j];
      rc1[j] = addv[b1 * NPAD + obase + j];
    }
    const size_t panelC = (size_t)rp * (size_t)(128 * KB);
    const size_t addrBase = panelC + (size_t)(po >> 5) * 4096 + (po & 7);
    const int slotb = (po >> 3) & 3;
    const int rowb7 = wm * 64 + ls * 4;
#pragma unroll
    for (int i = 0; i < 4; ++i) {
#pragma unroll
      for (int r = 0; r < 4; ++r) {
        const int r7 = rowb7 + i * 16 + r;
        const int row = row0 + r7;
        const bool useb0 = ((unsigned)row / 1000u) == b0;
        float v = acc[i][0][r] + (useb0 ? rc0[0] : rc1[0]);
        v = fmaxf(v, acc[i][1][r] + (useb0 ? rc0[1] : rc1[1]));
        v = fmaxf(v, acc[i][2][r] + (useb0 ? rc0[2] : rc1[2]));
        v = fmaxf(v, acc[i][3][r] + (useb0 ? rc0[3] : rc1[3]));
        const int sw = (r7 >> 1) & 3;
        size_t addr = addrBase + r7 * 32 + ((slotb ^ sw) << 3);
        unsigned short hh, ll;
        split2(v, hh, ll);
        Couth[addr] = hh;
        Coutl[addr] = ll;
      }
    }
  } else {
    const int colb = n0 + wn * 64 + lr;
    const int rowb7 = wm * 64 + ls * 4;
    const int pmine = lane & 3;
    float w12j[4], addj[4];
#pragma unroll
    for (int j = 0; j < 4; ++j) {
      const int col = colb + j * 16;
      w12j[j] = (col < 800) ? W12[pmine * 400 + 200 + (col >> 2)] : 0.f;
      addj[j] = (col < 800) ? addv[col] : 0.f;
    }
    const int slice = np * 2 + wn;
#pragma unroll
    for (int i = 0; i < 4; ++i) {
#pragma unroll
      for (int r = 0; r < 4; ++r) {
        const int row = row0 + rowb7 + i * 16 + r;
        float sp = 0.f;
#pragma unroll
        for (int j = 0; j < 4; ++j) {
          float v = acc[i][j][r] + addj[j];
          v = fmaxf(v, __shfl_xor(v, 1));
          v = fmaxf(v, __shfl_xor(v, 2));
          sp = fmaf(v, w12j[j], sp);
        }
        sp += __shfl_xor(sp, 4);
        sp += __shfl_xor(sp, 8);
        if (lr < 4)
          partial[((size_t)row * 14 + slice) * 4 + lr] = sp;
      }
    }
  }
}

// ---------------------------------------------------------------- alpha: m1.W12 + slices + b12 (direct-read, 1 thread = 1 row)
__global__ __launch_bounds__(256) void k_alphad(
    const unsigned short* __restrict__ m1h, const unsigned short* __restrict__ m1l,
    const float* __restrict__ partial, const float* __restrict__ W12,
    const float* __restrict__ b12, float* __restrict__ alpha) {
  __shared__ float w12s[896];
  const int t = threadIdx.x;
  for (int i = t; i < 896; i += 256) {
    int p = i / 224, k = i - p * 224;
    w12s[i] = (k < 200) ? W12[p * 400 + k] : 0.f;
  }
  __syncthreads();
  const int row = blockIdx.x * 256 + t;
  const int rp = row >> 7, r7 = row & 127;
  const int sw = (r7 >> 1) & 3;
  const size_t panelC = (size_t)rp * (size_t)(128 * KB);
  float4 bb = *(const float4*)b12;
  float a0 = bb.x, a1 = bb.y, a2 = bb.z, a3 = bb.w;
#pragma unroll
  for (int kt = 0; kt < 7; ++kt) {
    const size_t tb = panelC + (size_t)kt * 4096 + r7 * 32;
#pragma unroll
    for (int c = 0; c < 4; ++c) {
      const short8 hv = *(const short8*)(m1h + tb + ((c ^ sw) << 3));
      const short8 lv = *(const short8*)(m1l + tb + ((c ^ sw) << 3));
      const int kb = kt * 32 + c * 8;
#pragma unroll
      for (int e = 0; e < 8; ++e) {
        float val = bf2f((unsigned short)hv[e]) + bf2f((unsigned short)lv[e]);
        a0 = fmaf(val, w12s[kb + e], a0);
        a1 = fmaf(val, w12s[224 + kb + e], a1);
        a2 = fmaf(val, w12s[448 + kb + e], a2);
        a3 = fmaf(val, w12s[672 + kb + e], a3);
      }
    }
  }
  const float4* pr = (const float4*)(partial + (size_t)row * 56);
#pragma unroll
  for (int s = 0; s < 14; ++s) {
    float4 p4 = pr[s];
    a0 += p4.x; a1 += p4.y; a2 += p4.z; a3 += p4.w;
  }
  alpha[row] = fmaxf(fmaxf(a0, a1), fmaxf(a2, a3));
}

// ---------------------------------------------------------------- argmax + logsumexp (alpha input)
__global__ __launch_bounds__(256) void k_argmax(const float* __restrict__ alpha,
    const int* __restrict__ dmask, const int* __restrict__ span, int tag,
    int* __restrict__ idx_out, float* __restrict__ atgt_out) {
  int b = blockIdx.x, t = threadIdx.x;
  __shared__ float vals[MM];
  __shared__ float rv[256];
  __shared__ int ri[256];
  float bestv = -3.4e38f; int besti = 0x7fffffff;
  for (int m = t; m < MM; m += 256) {
    float v = alpha[b * MM + m];
    if (!dmask[b * MM + m]) v += NEGV;
    vals[m] = v;
    if (v > bestv || (v == bestv && m < besti)) { bestv = v; besti = m; }
  }
  rv[t] = bestv; ri[t] = besti; __syncthreads();
  for (int s = 128; s > 0; s >>= 1) {
    if (t < s) {
      float v2 = rv[t + s]; int i2 = ri[t + s];
      if (v2 > rv[t] || (v2 == rv[t] && i2 < ri[t])) { rv[t] = v2; ri[t] = i2; }
    }
    __syncthreads();
  }
  float vmax = rv[0]; int vidx = ri[0];
  __syncthreads();
  float se = 0.f;
  for (int m = t; m < MM; m += 256) se += expf(vals[m] - vmax);
  rv[t] = se; __syncthreads();
  for (int s = 128; s > 0; s >>= 1) { if (t < s) rv[t] += rv[t + s]; __syncthreads(); }
  if (t == 0) {
    int tgt = span[b * 2 + tag];
    atgt_out[b] = vals[tgt] - vmax - logf(rv[0]);
    idx_out[b] = vidx;
  }
}

// ================= fallback GEMM + reduce =================
template <int MODE, int PRESPLIT>
__global__ __launch_bounds__(256) void k_mgemm(
    const float* __restrict__ Af, int lda, int KsrcA,
    const unsigned short* __restrict__ Ah, const unsigned short* __restrict__ Al,
    const unsigned short* __restrict__ Bh, const unsigned short* __restrict__ Bl, int Kpad,
    const float* __restrict__ addv,
    unsigned short* __restrict__ Couth, unsigned short* __restrict__ Coutl,
    float* __restrict__ partial, const float* __restrict__ W12, int slice_base) {
  __shared__ unsigned short sAh[128 * LSTR], sAl[128 * LSTR];
  __shared__ unsigned short sBh[128 * LSTR], sBl[128 * LSTR];
  const int tid = threadIdx.x;
  const int lane = tid & 63, wave = tid >> 6;
  const int wm = wave >> 1, wn = wave & 1;
  const int n0 = blockIdx.x * 128, row0 = blockIdx.y * 128;
  const int lr = lane & 15, ls = lane >> 4;
  f32x4 acc[4][4];
#pragma unroll
  for (int i = 0; i < 4; ++i)
#pragma unroll
    for (int j = 0; j < 4; ++j) acc[i][j] = (f32x4){0.f, 0.f, 0.f, 0.f};
  const int srow = tid >> 1, shalf = tid & 1;
  const float* Afp = Af ? (Af + (size_t)(row0 + srow) * lda + shalf * 16) : nullptr;
  const unsigned short* Ahp = Ah ? (Ah + (size_t)(row0 + srow) * Kpad + shalf * 16) : nullptr;
  const unsigned short* Alp = Al ? (Al + (size_t)(row0 + srow) * Kpad + shalf * 16) : nullptr;
  const unsigned short* Bhp = Bh + (size_t)(n0 + srow) * Kpad + shalf * 16;
  const unsigned short* Blp = Bl + (size_t)(n0 + srow) * Kpad + shalf * 16;
  const int wo = srow * LSTR + shalf * 16;
  const int aoff = (wm * 64 + lr) * LSTR + ls * 8;
  const int boff = (wn * 64 + lr) * LSTR + ls * 8;
  short8 rah0, rah1, ral0, ral1, rbh0, rbh1, rbl0, rbl1;
  auto loadk = [&](int kt) {
    if (PRESPLIT) {
      rah0 = *(const short8*)(Ahp + kt * 32);
      rah1 = *(const short8*)(Ahp + kt * 32 + 8);
      ral0 = *(const short8*)(Alp + kt * 32);
      ral1 = *(const short8*)(Alp + kt * 32 + 8);
    } else {
      const int kk = kt * 32 + shalf * 16;
      float av[16];
#pragma unroll
      for (int q = 0; q < 4; ++q) {
        float4 v;
        if (kk + q * 4 + 4 <= KsrcA) v = *(const float4*)(Afp + kt * 32 + q * 4);
        else v = make_float4(0.f, 0.f, 0.f, 0.f);
        av[q * 4 + 0] = v.x; av[q * 4 + 1] = v.y;
        av[q * 4 + 2] = v.z; av[q * 4 + 3] = v.w;
      }
#pragma unroll
      for (int e = 0; e < 8; ++e) {
        unsigned short hh, ll;
        split2(av[e], hh, ll);     rah0[e] = (short)hh; ral0[e] = (short)ll;
        split2(av[8 + e], hh, ll); rah1[e] = (short)hh; ral1[e] = (short)ll;
      }
    }
    rbh0 = *(const short8*)(Bhp + kt * 32);
    rbh1 = *(const short8*)(Bhp + kt * 32 + 8);
    rbl0 = *(const short8*)(Blp + kt * 32);
    rbl1 = *(const short8*)(Blp + kt * 32 + 8);
  };
  const int nk = Kpad >> 5;
  loadk(0);
  for (int kt = 0; kt < nk; ++kt) {
    *(short8*)&sAh[wo] = rah0; *(short8*)&sAh[wo + 8] = rah1;
    *(short8*)&sAl[wo] = ral0; *(short8*)&sAl[wo + 8] = ral1;
    *(short8*)&sBh[wo] = rbh0; *(short8*)&sBh[wo + 8] = rbh1;
    *(short8*)&sBl[wo] = rbl0; *(short8*)&sBl[wo + 8] = rbl1;
    __syncthreads();
    if (kt + 1 < nk) loadk(kt + 1);
    short8 fa[4], fb[4];
#pragma unroll
    for (int i = 0; i < 4; ++i) fa[i] = *(const short8*)&sAh[aoff + i * 16 * LSTR];
#pragma unroll
    for (int j = 0; j < 4; ++j) fb[j] = *(const short8*)&sBh[boff + j * 16 * LSTR];
#pragma unroll
    for (int i = 0; i < 4; ++i)
#pragma unroll
      for (int j = 0; j < 4; ++j)
        acc[i][j] = __builtin_amdgcn_mfma_f32_16x16x32_bf16(fa[i], fb[j], acc[i][j], 0, 0, 0);
    short8 fc[4];
#pragma unroll
    for (int j = 0; j < 4; ++j) fc[j] = *(const short8*)&sBl[boff + j * 16 * LSTR];
#pragma unroll
    for (int i = 0; i < 4; ++i)
#pragma unroll
      for (int j = 0; j < 4; ++j)
        acc[i][j] = __builtin_amdgcn_mfma_f32_16x16x32_bf16(fa[i], fc[j], acc[i][j], 0, 0, 0);
#pragma unroll
    for (int i = 0; i < 4; ++i) fa[i] = *(const short8*)&sAl[aoff + i * 16 * LSTR];
#pragma unroll
    for (int i = 0; i < 4; ++i)
#pragma unroll
      for (int j = 0; j < 4; ++j)
        acc[i][j] = __builtin_amdgcn_mfma_f32_16x16x32_bf16(fa[i], fb[j], acc[i][j], 0, 0, 0);
    __syncthreads();
  }
  const int colb = n0 + wn * 64 + lr;
  const int rowb = row0 + wm * 64 + ls * 4;
  const int pmine = lane & 3;
  const int woff = (MODE == 0) ? 0 : 200;
  float w12j[4], addj[4];
#pragma unroll
  for (int j = 0; j < 4; ++j) {
    const int col = colb + j * 16;
    w12j[j] = (col < 800) ? W12[pmine * 400 + woff + (col >> 2)] : 0.f;
    if (MODE == 1) addj[j] = (col < 800) ? addv[col] : 0.f;
  }
  const int slice = slice_base + blockIdx.x * 2 + wn;
#pragma unroll
  for (int i = 0; i < 4; ++i) {
#pragma unroll
    for (int r = 0; r < 4; ++r) {
      const int row = rowb + i * 16 + r;
      float sp = 0.f;
#pragma unroll
      for (int j = 0; j < 4; ++j) {
        const int col = colb + j * 16;
        float v = acc[i][j][r];
        if (MODE == 0) {
          const unsigned bidx = (unsigned)row / 1000u;
          v += addv[bidx * NPAD + col];
        } else {
          v += addj[j];
        }
        v = fmaxf(v, __shfl_xor(v, 1));
        v = fmaxf(v, __shfl_xor(v, 2));
        if (MODE == 0 && (lane & 3) == 0) {
          unsigned short hh, ll;
          split2(v, hh, ll);
          Couth[(size_t)row * KB + (col >> 2)] = hh;
          Coutl[(size_t)row * KB + (col >> 2)] = ll;
        }
        sp = fmaf(v, w12j[j], sp);
      }
      sp += __shfl_xor(sp, 4);
      sp += __shfl_xor(sp, 8);
      if (lr < 4)
        partial[((size_t)row * NSLICE + slice) * 4 + lr] = sp;
    }
  }
}

__global__ __launch_bounds__(256) void k_reduce(const float* __restrict__ partial,
    const float* __restrict__ b12, const int* __restrict__ dmask,
    const int* __restrict__ span, int tag,
    int* __restrict__ idx_out, float* __restrict__ atgt_out) {
  int b = blockIdx.x, t = threadIdx.x;
  __shared__ float vals[MM];
  __shared__ float rv[256];
  __shared__ int ri[256];
  float4 bb = *(const float4*)b12;
  float bestv = -3.4e38f; int besti = 0x7fffffff;
  for (int m = t; m < MM; m += 256) {
    const float4* pr = (const float4*)(partial + ((size_t)(b * MM + m)) * (NSLICE * 4));
    float4 a4 = bb;
#pragma unroll
    for (int s = 0; s < NSLICE; ++s) {
      float4 p4 = pr[s];
      a4.x += p4.x; a4.y += p4.y; a4.z += p4.z; a4.w += p4.w;
    }
    float v = fmaxf(fmaxf(a4.x, a4.y), fmaxf(a4.z, a4.w));
    if (!dmask[b * MM + m]) v += NEGV;
    vals[m] = v;
    if (v > bestv || (v == bestv && m < besti)) { bestv = v; besti = m; }
  }
  rv[t] = bestv; ri[t] = besti; __syncthreads();
  for (int s = 128; s > 0; s >>= 1) {
    if (t < s) {
      float v2 = rv[t + s]; int i2 = ri[t + s];
      if (v2 > rv[t] || (v2 == rv[t] && i2 < ri[t])) { rv[t] = v2; ri[t] = i2; }
    }
    __syncthreads();
  }
  float vmax = rv[0]; int vidx = ri[0];
  __syncthreads();
  float se = 0.f;
  for (int m = t; m < MM; m += 256) se += expf(vals[m] - vmax);
  rv[t] = se; __syncthreads();
  for (int s = 128; s > 0; s >>= 1) { if (t < s) rv[t] += rv[t + s]; __syncthreads(); }
  if (t == 0) {
    int tgt = span[b * 2 + tag];
    atgt_out[b] = vals[tgt] - vmax - logf(rv[0]);
    idx_out[b] = vidx;
  }
}

// ---------------------------------------------------------------- state update + loss
__global__ __launch_bounds__(64) void k_update(const int* __restrict__ idx_buf,
    const float* __restrict__ atgt, int* __restrict__ st, int* __restrict__ mstate,
    float* __restrict__ pout, float* __restrict__ loss, int first) {
  int b = threadIdx.x;
  int idx = idx_buf[b];
  int sold = st[b], msold = mstate[b];
  int snew = first ? idx : (msold ? idx : 0);
  int msnew = first ? 1 : ((snew != (msold ? sold : 0)) ? 1 : 0);
  st[b] = snew; mstate[b] = msnew;
  if (msnew) pout[b] = (float)snew;
  float asum = atgt[b];
  float csum = (float)msnew;
  for (int off = 32; off > 0; off >>= 1) {
    asum += __shfl_down(asum, off);
    csum += __shfl_down(csum, off);
  }
  if (b == 0) loss[0] += (-asum / (float)BB) * csum / (float)(BB * TT);
}

// ---------------------------------------------------------------- launch
extern "C" void kernel_launch(void* const* d_in, const int* in_sizes, int n_in,
                              void* d_out, int out_size, void* d_ws, size_t ws_size,
                              hipStream_t stream) {
  const float* U     = (const float*)d_in[0];
  const int*   dmask = (const int*)d_in[1];
  const int*   span  = (const int*)d_in[2];
  const float* w_ih  = (const float*)d_in[3];
  const float* w_hh  = (const float*)d_in[4];
  const float* b_ih  = (const float*)d_in[5];
  const float* b_hh  = (const float*)d_in[6];
  const float* Wr[2]  = {(const float*)d_in[7],  (const float*)d_in[14]};
  const float* W1[2]  = {(const float*)d_in[8],  (const float*)d_in[15]};
  const float* b1[2]  = {(const float*)d_in[9],  (const float*)d_in[16]};
  const float* W2[2]  = {(const float*)d_in[10], (const float*)d_in[17]};
  const float* b2[2]  = {(const float*)d_in[11], (const float*)d_in[18]};
  const float* W12[2] = {(const float*)d_in[12], (const float*)d_in[19]};
  const float* b12[2] = {(const float*)d_in[13], (const float*)d_in[20]};
  float* out = (float*)d_out;

  size_t off = 0;
  char* base = (char*)d_ws;
  auto alloc = [&](size_t n) {
    void* p = base + off;
    off += (n + 255) & ~(size_t)255;
    return p;
  };
  float* rcorr = (float*)alloc((size_t)BB * NPAD * 4);
  float* ue    = (float*)alloc((size_t)BB * 400 * 4);
  float* ucat  = (float*)alloc((size_t)BB * 800 * 4);
  float* gbuf  = (float*)alloc((size_t)BB * 800 * 4);
  float* rbuf  = (float*)alloc((size_t)BB * 200 * 4);
  float* hbuf  = (float*)alloc((size_t)BB * H * 4);
  float* cbuf  = (float*)alloc((size_t)BB * H * 4);
  float* alphab = (float*)alloc((size_t)ROWS * 4);
  float* atgt  = (float*)alloc((size_t)BB * 4);
  int* st_s = (int*)alloc(BB * 4);
  int* st_e = (int*)alloc(BB * 4);
  int* msb  = (int*)alloc(BB * 4);
  int* meb  = (int*)alloc(BB * 4);
  int* idxb = (int*)alloc(BB * 4);
  unsigned short *W1h[2], *W1l[2], *W2h[2], *W2l[2];
  for (int g = 0; g < 2; ++g) {
    W1h[g] = (unsigned short*)alloc((size_t)NPAD * KA * 2);
    W1l[g] = (unsigned short*)alloc((size_t)NPAD * KA * 2);
    W2h[g] = (unsigned short*)alloc((size_t)NPAD * KB * 2);
    W2l[g] = (unsigned short*)alloc((size_t)NPAD * KB * 2);
  }
  unsigned short* m1h = (unsigned short*)alloc((size_t)ROWS * KB * 2);
  unsigned short* m1l = (unsigned short*)alloc((size_t)ROWS * KB * 2);

  const size_t P14_B  = (size_t)ROWS * 14 * 4 * 4;
  const size_t TIH_B  = (size_t)800 * 800 * 4;
  const size_t THH_B  = (size_t)200 * 800 * 4;
  const size_t TWR_B  = (size_t)1000 * 200 * 4;
  const size_t TW1_B  = (size_t)200 * 800 * 4;
  const size_t UHL_B  = (size_t)ROWS * KA * 2;
  size_t panel_need = off + P14_B + TIH_B + THH_B + 2 * TWR_B + 2 * TW1_B + 2 * UHL_B + 4096;
  bool panelPath = (ws_size >= panel_need);

  if (panelPath) {
    float* partial = (float*)alloc(P14_B);
    float* wTih = (float*)alloc(TIH_B);
    float* wThh = (float*)alloc(THH_B);
    float* WrT[2]  = {(float*)alloc(TWR_B), (float*)alloc(TWR_B)};
    float* W1cT[2] = {(float*)alloc(TW1_B), (float*)alloc(TW1_B)};
    unsigned short* Uh = (unsigned short*)alloc(UHL_B);
    unsigned short* Ul = (unsigned short*)alloc(UHL_B);

    k_init<<<BB, 256, 0, stream>>>(dmask, st_s, st_e, msb, meb, hbuf, cbuf, out);
    for (int g = 0; g < 2; ++g) {
      k_splitPW1<<<NPAD, 256, 0, stream>>>(W1[g], W1h[g], W1l[g]);
      k_splitP<<<NPAD, 256, 0, stream>>>(W2[g], 200, 200, 800, W2h[g], W2l[g], KB);
      k_T<<<1000, 256, 0, stream>>>(Wr[g], 1000, 200, 0, WrT[g]);
      k_T<<<200, 256, 0, stream>>>(W1[g], 600, 800, 400, W1cT[g]);
    }
    k_T<<<800, 256, 0, stream>>>(w_ih, 800, 800, 0, wTih);
    k_T<<<200, 256, 0, stream>>>(w_hh, 200, 800, 0, wThh);
    k_splitP<<<ROWS, 256, 0, stream>>>(U, 400, 400, ROWS, Uh, Ul, KA);

    dim3 g13(13, BB), g4(4, BB), g14(14, BB);
    for (int t = 0; t < TT; ++t) {
      int first = (t == 0) ? 1 : 0;
      // ---- tag s ----
      k_prep<<<BB, 256, 0, stream>>>(U, st_s, st_e, ucat, ue);
      k_gates<<<g13, 256, 0, stream>>>(ucat, hbuf, wTih, wThh, b_ih, b_hh, gbuf);
      k_act<<<BB, 256, 0, stream>>>(gbuf, hbuf, cbuf);
      k_r2<0><<<g4, 256, 0, stream>>>(U, st_s, ucat, ue, hbuf, WrT[0], rbuf);
      k_rcorr<<<g14, 256, 0, stream>>>(rbuf, W1cT[0], b1[0], rcorr);
      k_pgemm<0><<<GG, 256, 0, stream>>>(Uh, Ul, W1h[0], W1l[0],
          rcorr, m1h, m1l, nullptr, nullptr);
      k_pgemm<1><<<GG, 256, 0, stream>>>(m1h, m1l, W2h[0], W2l[0],
          b2[0], nullptr, nullptr, partial, W12[0]);
      k_alphad<<<ROWS / 256, 256, 0, stream>>>(m1h, m1l, partial, W12[0], b12[0], alphab);
      k_argmax<<<BB, 256, 0, stream>>>(alphab, dmask, span, 0, idxb, atgt);
      k_update<<<1, 64, 0, stream>>>(idxb, atgt, st_s, msb, out + 1, out, first);
      // ---- tag e ----
      k_r2<1><<<g4, 256, 0, stream>>>(U, st_s, ucat, ue, hbuf, WrT[1], rbuf);
      k_rcorr<<<g14, 256, 0, stream>>>(rbuf, W1cT[1], b1[1], rcorr);
      k_pgemm<0><<<GG, 256, 0, stream>>>(Uh, Ul, W1h[1], W1l[1],
          rcorr, m1h, m1l, nullptr, nullptr);
      k_pgemm<1><<<GG, 256, 0, stream>>>(m1h, m1l, W2h[1], W2l[1],
          b2[1], nullptr, nullptr, partial, W12[1]);
      k_alphad<<<ROWS / 256, 256, 0, stream>>>(m1h, m1l, partial, W12[1], b12[1], alphab);
      k_argmax<<<BB, 256, 0, stream>>>(alphab, dmask, span, 1, idxb, atgt);
      k_update<<<1, 64, 0, stream>>>(idxb, atgt, st_e, meb, out + 1 + BB, out, first);
    }
  } else {
    // fallback: round-7 path
    float* partial = (float*)alloc((size_t)ROWS * NSLICE * 4 * 4);
    k_init<<<BB, 256, 0, stream>>>(dmask, st_s, st_e, msb, meb, hbuf, cbuf, out);
    for (int g = 0; g < 2; ++g) {
      k_split<<<NPAD, 256, 0, stream>>>(W1[g], 600, 400, 800, W1h[g], W1l[g], KA);
      k_split<<<NPAD, 256, 0, stream>>>(W2[g], 200, 200, 800, W2h[g], W2l[g], KB);
    }
    dim3 gg(NPAD / 128, ROWS / 128);
    for (int t = 0; t < TT; ++t) {
      int first = (t == 0) ? 1 : 0;
      for (int tag = 0; tag < 2; ++tag) {
        if (tag == 0)
          k_lstm_r<<<BB, 1024, 0, stream>>>(U, st_s, st_e, hbuf, cbuf, w_ih, w_hh, b_ih, b_hh,
                                            Wr[0], W1[0], b1[0], rcorr, ue);
        else
          k_re<<<BB, 1024, 0, stream>>>(U, st_s, ue, hbuf, Wr[1], W1[1], b1[1], rcorr);

        k_mgemm<0, 0><<<gg, 256, 0, stream>>>(U, 400, 400, nullptr, nullptr,
            W1h[tag], W1l[tag], KA, rcorr, m1h, m1l, partial, W12[tag], 0);
        k_mgemm<1, 1><<<gg, 256, 0, stream>>>(nullptr, 0, 0, m1h, m1l,
            W2h[tag], W2l[tag], KB, b2[tag], nullptr, nullptr, partial, W12[tag], 14);

        k_reduce<<<BB, 256, 0, stream>>>(partial, b12[tag], dmask, span, tag, idxb, atgt);
        if (tag == 0)
          k_update<<<1, 64, 0, stream>>>(idxb, atgt, st_s, msb, out + 1, out, first);
        else
          k_update<<<1, 64, 0, stream>>>(idxb, atgt, st_e, meb, out + 1 + BB, out, first);
      }
    }
  }
}

// Round 11
// 2037.319 us; speedup vs baseline: 2.6814x; 2.6814x over previous
//
#include <hip/hip_runtime.h>
#include <math.h>

#define H 200
#define TT 4
#define BB 64
#define MM 1000
#define NEGV (-1e30f)

static const int ROWS = BB * MM;   // 64000
#define KA 416                     // 400 padded to x32
#define KB 224                     // 200 padded to x32
#define NPAD 896                   // 800 padded to 7*128
#define NSLICE 28                  // fallback partial slices
#define LSTR 40                    // fallback kernel LDS row stride (ushorts)
#define RP 500                     // row panels
#define GG 3528                    // 63 groups * 56 (8 rp x 7 np), rp>=500 guarded

typedef __attribute__((ext_vector_type(8))) short short8;
typedef __attribute__((ext_vector_type(4))) float f32x4;

__device__ __forceinline__ void split2(float x, unsigned short& h, unsigned short& l) {
  unsigned u = __float_as_uint(x);
  h = (unsigned short)(u >> 16);
  float res = x - __uint_as_float(u & 0xffff0000u);
  l = (unsigned short)(__float_as_uint(res) >> 16);
}
__device__ __forceinline__ float bf2f(unsigned short h) {
  return __uint_as_float(((unsigned)h) << 16);
}
__device__ __forceinline__ void gload16(const unsigned short* g, const unsigned short* l) {
  __builtin_amdgcn_global_load_lds(
      (const __attribute__((address_space(1))) void*)g,
      (__attribute__((address_space(3))) void*)l, 16, 0, 0);
}

// ---------------------------------------------------------------- init
__global__ __launch_bounds__(256) void k_init(const int* __restrict__ dmask,
    int* st_s, int* st_e, int* ms, int* me,
    float* h, float* c, float* out) {
  int b = blockIdx.x, t = threadIdx.x;
  __shared__ int red[256];
  int sum = 0;
  for (int m = t; m < MM; m += 256) sum += dmask[b * MM + m];
  red[t] = sum; __syncthreads();
  for (int s = 128; s > 0; s >>= 1) { if (t < s) red[t] += red[t + s]; __syncthreads(); }
  if (t == 0) { st_s[b] = 0; st_e[b] = red[0] - 1; ms[b] = 1; me[b] = 1; }
  for (int i = t; i < H; i += 256) { h[b * H + i] = 0.f; c[b * H + i] = 0.f; }
  if (b == 0 && t == 0) out[0] = 0.f;
}

// ---------------------------------------------------------------- transpose: dst[k][r]=src[r][koff+k]
__global__ __launch_bounds__(256) void k_T(const float* __restrict__ src, int ld,
    int R, int koff, float* __restrict__ dst) {
  int k = blockIdx.x;
  for (int r = threadIdx.x; r < R; r += 256)
    dst[(size_t)k * R + r] = src[(size_t)r * ld + koff + k];
}

// ---------------------------------------------------------------- split -> swizzled panel format
__global__ __launch_bounds__(256) void k_splitP(const float* __restrict__ src, int srcld,
    int Ksrc, int Nsrc,
    unsigned short* __restrict__ hi, unsigned short* __restrict__ lo, int Kpad) {
  int r = blockIdx.x;
  int r7 = r & 127;
  size_t pbase = (size_t)(r >> 7) * (size_t)(128 * Kpad);
  int sw = (r7 >> 1) & 3;
  for (int k = threadIdx.x; k < Kpad; k += 256) {
    unsigned short h = 0, l = 0;
    if (r < Nsrc && k < Ksrc) split2(src[(size_t)r * srcld + k], h, l);
    size_t addr = pbase + (size_t)(k >> 5) * 4096 + r7 * 32 +
                  ((((k >> 3) & 3) ^ sw) << 3) + (k & 7);
    hi[addr] = h; lo[addr] = l;
  }
}

// W1 split with output-neuron permutation within 64-row groups
__global__ __launch_bounds__(256) void k_splitPW1(const float* __restrict__ src,
    unsigned short* __restrict__ hi, unsigned short* __restrict__ lo) {
  int r = blockIdx.x;
  int o = (r & ~63) + ((r & 15) << 2) + ((r >> 4) & 3);
  int r7 = r & 127;
  size_t pbase = (size_t)(r >> 7) * (size_t)(128 * KA);
  int sw = (r7 >> 1) & 3;
  for (int k = threadIdx.x; k < KA; k += 256) {
    unsigned short h = 0, l = 0;
    if (o < 800 && k < 400) split2(src[(size_t)o * 600 + k], h, l);
    size_t addr = pbase + (size_t)(k >> 5) * 4096 + r7 * 32 +
                  ((((k >> 3) & 3) ^ sw) << 3) + (k & 7);
    hi[addr] = h; lo[addr] = l;
  }
}

// ---------------------------------------------------------------- row-major weight split (fallback)
__global__ __launch_bounds__(256) void k_split(const float* __restrict__ src, int srcld,
    int Ksrc, int Nsrc,
    unsigned short* __restrict__ hi, unsigned short* __restrict__ lo, int Kpad) {
  int r = blockIdx.x;
  for (int k = threadIdx.x; k < Kpad; k += 256) {
    unsigned short h = 0, l = 0;
    if (r < Nsrc && k < Ksrc) split2(src[(size_t)r * srcld + k], h, l);
    hi[(size_t)r * Kpad + k] = h;
    lo[(size_t)r * Kpad + k] = l;
  }
}

// ================= split-K multi-block decoder chain =================
__global__ __launch_bounds__(256) void k_prep(const float* __restrict__ U,
    const int* __restrict__ st_s, const int* __restrict__ st_e,
    float* __restrict__ ucat, float* __restrict__ ue) {
  int b = blockIdx.x, t = threadIdx.x;
  int si = st_s[b], ei = st_e[b];
  const float* Us = U + ((size_t)b * MM + si) * 400;
  const float* Ue = U + ((size_t)b * MM + ei) * 400;
  for (int i = t; i < 400; i += 256) {
    float uv = Ue[i];
    ucat[b * 800 + i] = Us[i];
    ucat[b * 800 + 400 + i] = uv;
    ue[b * 400 + i] = uv;
  }
}

__global__ __launch_bounds__(256) void k_gates(
    const float* __restrict__ ucat, const float* __restrict__ hbuf,
    const float* __restrict__ wTih, const float* __restrict__ wThh,
    const float* __restrict__ b_ih, const float* __restrict__ b_hh,
    float* __restrict__ g) {
  const int b = blockIdx.y, t = threadIdx.x;
  const int o = blockIdx.x * 64 + (t & 63);
  const int oc = o < 800 ? o : 799;
  const int ks = t >> 6;
  __shared__ float xs[800], hs[200], red[256];
  for (int i = t; i < 800; i += 256) xs[i] = ucat[b * 800 + i];
  for (int i = t; i < 200; i += 256) hs[i] = hbuf[b * H + i];
  __syncthreads();
  float acc = 0.f;
#pragma unroll 8
  for (int k = ks * 200; k < ks * 200 + 200; ++k)
    acc = fmaf(wTih[(size_t)k * 800 + oc], xs[k], acc);
#pragma unroll 8
  for (int k = ks * 50; k < ks * 50 + 50; ++k)
    acc = fmaf(wThh[(size_t)k * 800 + oc], hs[k], acc);
  red[t] = acc; __syncthreads();
  if (ks == 0 && o < 800)
    g[b * 800 + o] = red[t] + red[t + 64] + red[t + 128] + red[t + 192] + b_ih[o] + b_hh[o];
}

__global__ __launch_bounds__(256) void k_act(const float* __restrict__ g,
    float* __restrict__ h, float* __restrict__ c) {
  int b = blockIdx.x, t = threadIdx.x;
  if (t >= H) return;
  float ig = 1.f / (1.f + expf(-g[b * 800 + t]));
  float fg = 1.f / (1.f + expf(-g[b * 800 + 200 + t]));
  float gg = tanhf(g[b * 800 + 400 + t]);
  float og = 1.f / (1.f + expf(-g[b * 800 + 600 + t]));
  float cn = fg * c[b * H + t] + ig * gg;
  c[b * H + t] = cn;
  h[b * H + t] = og * tanhf(cn);
}

template <int TAG>
__global__ __launch_bounds__(256) void k_r2(
    const float* __restrict__ U, const int* __restrict__ st_s,
    const float* __restrict__ ucat, const float* __restrict__ ue,
    const float* __restrict__ hbuf, const float* __restrict__ WrT,
    float* __restrict__ rbuf) {
  const int b = blockIdx.y, t = threadIdx.x;
  const int o = blockIdx.x * 64 + (t & 63);
  const int oc = o < 200 ? o : 199;
  const int ks = t >> 6;
  __shared__ float xcs[1000], red[256];
  for (int i = t; i < 200; i += 256) xcs[i] = hbuf[b * H + i];
  if (TAG == 0) {
    for (int i = t; i < 800; i += 256) xcs[200 + i] = ucat[b * 800 + i];
  } else {
    const float* Us = U + ((size_t)b * MM + st_s[b]) * 400;
    for (int i = t; i < 400; i += 256) {
      xcs[200 + i] = Us[i];
      xcs[600 + i] = ue[b * 400 + i];
    }
  }
  __syncthreads();
  float acc = 0.f;
#pragma unroll 8
  for (int k = ks * 250; k < ks * 250 + 250; ++k)
    acc = fmaf(WrT[(size_t)k * 200 + oc], xcs[k], acc);
  red[t] = acc; __syncthreads();
  if (ks == 0 && o < 200)
    rbuf[b * 200 + o] = tanhf(red[t] + red[t + 64] + red[t + 128] + red[t + 192]);
}

__global__ __launch_bounds__(256) void k_rcorr(
    const float* __restrict__ rbuf, const float* __restrict__ W1cT,
    const float* __restrict__ b1, float* __restrict__ rcorr) {
  const int b = blockIdx.y, t = threadIdx.x;
  const int o = blockIdx.x * 64 + (t & 63);
  const int oc = o < 800 ? o : 799;
  const int ks = t >> 6;
  __shared__ float rs[200], red[256];
  for (int i = t; i < 200; i += 256) rs[i] = rbuf[b * 200 + i];
  __syncthreads();
  float acc = 0.f;
#pragma unroll 8
  for (int k = ks * 50; k < ks * 50 + 50; ++k)
    acc = fmaf(W1cT[(size_t)k * 800 + oc], rs[k], acc);
  red[t] = acc; __syncthreads();
  if (ks == 0)
    rcorr[b * NPAD + o] = (o < 800)
        ? red[t] + red[t + 64] + red[t + 128] + red[t + 192] + b1[o] : 0.f;
}

// ================= fallback chain kernels (ws too small) =================
__global__ __launch_bounds__(1024) void k_lstm_r(
    const float* __restrict__ U, const int* __restrict__ st_s, const int* __restrict__ st_e,
    float* __restrict__ h, float* __restrict__ c,
    const float* __restrict__ w_ih, const float* __restrict__ w_hh,
    const float* __restrict__ b_ih, const float* __restrict__ b_hh,
    const float* __restrict__ Wr, const float* __restrict__ W1, const float* __restrict__ b1,
    float* __restrict__ rcorr, float* __restrict__ ue) {
  int b = blockIdx.x, t = threadIdx.x;
  __shared__ float xc[1000];
  __shared__ float hold[H];
  __shared__ float g[800];
  __shared__ float r[H];
  int si = st_s[b], ei = st_e[b];
  const float* Us = U + ((size_t)b * MM + si) * 400;
  const float* Ue = U + ((size_t)b * MM + ei) * 400;
  if (t < 400) { xc[200 + t] = Us[t]; xc[600 + t] = Ue[t]; ue[b * 400 + t] = Ue[t]; }
  if (t >= 400 && t < 600) hold[t - 400] = h[b * H + (t - 400)];
  __syncthreads();
  if (t < 800) {
    float acc = b_ih[t] + b_hh[t];
    const float4* wi = (const float4*)(w_ih + (size_t)t * 800);
    const float* xv = &xc[200];
    for (int k = 0; k < 200; ++k) {
      float4 wv = wi[k];
      acc = fmaf(wv.x, xv[k * 4 + 0], acc); acc = fmaf(wv.y, xv[k * 4 + 1], acc);
      acc = fmaf(wv.z, xv[k * 4 + 2], acc); acc = fmaf(wv.w, xv[k * 4 + 3], acc);
    }
    const float4* wh = (const float4*)(w_hh + (size_t)t * H);
    for (int k = 0; k < 50; ++k) {
      float4 wv = wh[k];
      acc = fmaf(wv.x, hold[k * 4 + 0], acc); acc = fmaf(wv.y, hold[k * 4 + 1], acc);
      acc = fmaf(wv.z, hold[k * 4 + 2], acc); acc = fmaf(wv.w, hold[k * 4 + 3], acc);
    }
    g[t] = acc;
  }
  __syncthreads();
  if (t < H) {
    float ig = 1.f / (1.f + expf(-g[t]));
    float fg = 1.f / (1.f + expf(-g[H + t]));
    float gg = tanhf(g[2 * H + t]);
    float og = 1.f / (1.f + expf(-g[3 * H + t]));
    float cn = fg * c[b * H + t] + ig * gg;
    c[b * H + t] = cn;
    float hv = og * tanhf(cn);
    h[b * H + t] = hv;
    xc[t] = hv;
  }
  __syncthreads();
  if (t < H) {
    float acc = 0.f;
    const float4* wr = (const float4*)(Wr + (size_t)t * 1000);
    for (int k = 0; k < 250; ++k) {
      float4 wv = wr[k];
      acc = fmaf(wv.x, xc[k * 4 + 0], acc); acc = fmaf(wv.y, xc[k * 4 + 1], acc);
      acc = fmaf(wv.z, xc[k * 4 + 2], acc); acc = fmaf(wv.w, xc[k * 4 + 3], acc);
    }
    r[t] = tanhf(acc);
  }
  __syncthreads();
  if (t < NPAD) {
    float acc = 0.f;
    if (t < 800) {
      acc = b1[t];
      const float4* w1 = (const float4*)(W1 + (size_t)t * 600 + 400);
      for (int k = 0; k < 50; ++k) {
        float4 wv = w1[k];
        acc = fmaf(wv.x, r[k * 4 + 0], acc); acc = fmaf(wv.y, r[k * 4 + 1], acc);
        acc = fmaf(wv.z, r[k * 4 + 2], acc); acc = fmaf(wv.w, r[k * 4 + 3], acc);
      }
    }
    rcorr[b * NPAD + t] = acc;
  }
}

__global__ __launch_bounds__(1024) void k_re(
    const float* __restrict__ U, const int* __restrict__ st_s,
    const float* __restrict__ ue, const float* __restrict__ h,
    const float* __restrict__ Wr, const float* __restrict__ W1, const float* __restrict__ b1,
    float* __restrict__ rcorr) {
  int b = blockIdx.x, t = threadIdx.x;
  __shared__ float xc[1000];
  __shared__ float r[H];
  const float* Us = U + ((size_t)b * MM + st_s[b]) * 400;
  if (t < 200) xc[t] = h[b * H + t];
  if (t >= 200 && t < 600) xc[t] = Us[t - 200];
  if (t >= 600 && t < 1000) xc[t] = ue[b * 400 + (t - 600)];
  __syncthreads();
  if (t < H) {
    float acc = 0.f;
    const float4* wr = (const float4*)(Wr + (size_t)t * 1000);
    for (int k = 0; k < 250; ++k) {
      float4 wv = wr[k];
      acc = fmaf(wv.x, xc[k * 4 + 0], acc); acc = fmaf(wv.y, xc[k * 4 + 1], acc);
      acc = fmaf(wv.z, xc[k * 4 + 2], acc); acc = fmaf(wv.w, xc[k * 4 + 3], acc);
    }
    r[t] = tanhf(acc);
  }
  __syncthreads();
  if (t < NPAD) {
    float acc = 0.f;
    if (t < 800) {
      acc = b1[t];
      const float4* w1 = (const float4*)(W1 + (size_t)t * 600 + 400);
      for (int k = 0; k < 50; ++k) {
        float4 wv = w1[k];
        acc = fmaf(wv.x, r[k * 4 + 0], acc); acc = fmaf(wv.y, r[k * 4 + 1], acc);
        acc = fmaf(wv.z, r[k * 4 + 2], acc); acc = fmaf(wv.w, r[k * 4 + 3], acc);
      }
    }
    rcorr[b * NPAD + t] = acc;
  }
}

// ---------------------------------------------------------------- panel MFMA GEMM
// A and B single-buffered via gload_lds; fragments lifted to regs between
// barrier1/barrier2, next-tile DMA issued after barrier2 -> 32KB LDS.
// __launch_bounds__(256,4): 4 waves/EU -> VGPR cap 128 (no spill; (256,5) forced
// <64 VGPR and spilled the accumulator -> 844MB scratch traffic, round-10 lesson).
// MODE 0: permuted W1 -> in-register maxpool, write m1 panels. No partials.
// MODE 1: W2 -> shfl pooling + alpha slices 0..13 (stride 14).
template <int MODE>
__global__ __launch_bounds__(256, 4) void k_pgemm(
    const unsigned short* __restrict__ Ah, const unsigned short* __restrict__ Al,
    const unsigned short* __restrict__ Bh, const unsigned short* __restrict__ Bl,
    const float* __restrict__ addv,
    unsigned short* __restrict__ Couth, unsigned short* __restrict__ Coutl,
    float* __restrict__ partial, const float* __restrict__ W12) {
  const int Kpad = (MODE == 0) ? KA : KB;
  const int nk = Kpad >> 5;
  __shared__ unsigned short sA[8192];   // [hi 4096 | lo 4096]
  __shared__ unsigned short sB[8192];
  const int id = blockIdx.x;
  const int g = id / 56, rem = id % 56;
  const int np = rem >> 3, c8 = rem & 7;
  const int rp = g * 8 + c8;
  if (rp >= RP) return;
  const int tid = threadIdx.x;
  const int lane = tid & 63, wave = tid >> 6;
  const int wm = wave >> 1, wn = wave & 1;
  const int row0 = rp * 128, n0 = np * 128;
  const int lr = lane & 15, ls = lane >> 4;
  const size_t panelA = (size_t)rp * (size_t)(128 * Kpad);
  const size_t panelB = (size_t)np * (size_t)(128 * Kpad);
  const int aoff = (wm * 64 + lr) * 32 + ((ls ^ ((lr >> 1) & 3)) << 3);
  const int boff = (wn * 64 + lr) * 32 + ((ls ^ ((lr >> 1) & 3)) << 3);

  f32x4 acc[4][4];
#pragma unroll
  for (int i = 0; i < 4; ++i)
#pragma unroll
    for (int j = 0; j < 4; ++j) acc[i][j] = (f32x4){0.f, 0.f, 0.f, 0.f};

  auto issueA = [&](int kt) {
    const size_t tA = panelA + (size_t)kt * 4096;
#pragma unroll
    for (int q = 0; q < 2; ++q) {
      const int cc = (q * 4 + wave) * 512;
      gload16(Ah + tA + cc + lane * 8, &sA[cc]);
      gload16(Al + tA + cc + lane * 8, &sA[4096 + cc]);
    }
  };
  auto issueB = [&](int kt) {
    const size_t tB = panelB + (size_t)kt * 4096;
#pragma unroll
    for (int q = 0; q < 2; ++q) {
      const int cc = (q * 4 + wave) * 512;
      gload16(Bh + tB + cc + lane * 8, &sB[cc]);
      gload16(Bl + tB + cc + lane * 8, &sB[4096 + cc]);
    }
  };

  issueA(0);
  issueB(0);
  for (int kt = 0; kt < nk; ++kt) {
    __syncthreads();                       // barrier1: this tile's DMAs complete
    short8 bh[4], bl[4], fah[4], fal[4];
#pragma unroll
    for (int j = 0; j < 4; ++j) {
      bh[j] = *(const short8*)(sB + boff + j * 512);
      bl[j] = *(const short8*)(sB + 4096 + boff + j * 512);
    }
#pragma unroll
    for (int i = 0; i < 4; ++i) {
      fah[i] = *(const short8*)(sA + aoff + i * 512);
      fal[i] = *(const short8*)(sA + 4096 + aoff + i * 512);
    }
    __syncthreads();                       // barrier2: all waves done reading LDS
    if (kt + 1 < nk) { issueA(kt + 1); issueB(kt + 1); }  // overwrite under MFMA
#pragma unroll
    for (int i = 0; i < 4; ++i)
#pragma unroll
      for (int j = 0; j < 4; ++j)
        acc[i][j] = __builtin_amdgcn_mfma_f32_16x16x32_bf16(fah[i], bh[j], acc[i][j], 0, 0, 0);
#pragma unroll
    for (int i = 0; i < 4; ++i)
#pragma unroll
      for (int j = 0; j < 4; ++j)
        acc[i][j] = __builtin_amdgcn_mfma_f32_16x16x32_bf16(fah[i], bl[j], acc[i][j], 0, 0, 0);
#pragma unroll
    for (int i = 0; i < 4; ++i)
#pragma unroll
      for (int j = 0; j < 4; ++j)
        acc[i][j] = __builtin_amdgcn_mfma_f32_16x16x32_bf16(fal[i], bh[j], acc[i][j], 0, 0, 0);
  }

  if (MODE == 0) {
    const int obase = n0 + wn * 64 + lr * 4;
    const int po = ((n0 + wn * 64) >> 2) + lr;
    const unsigned b0 = (unsigned)row0 / 1000u;
    const unsigned b1 = (unsigned)(row0 + 127) / 1000u;
    float rc0[4], rc1[4];
#pragma unroll
    for (int j = 0; j < 4; ++j) {
      rc0[j] = addv[b0 * NPAD + obase + j];
      rc1[j] = addv[b1 * NPAD + obase + j];
    }
    const size_t panelC = (size_t)rp * (size_t)(128 * KB);
    const size_t addrBase = panelC + (size_t)(po >> 5) * 4096 + (po & 7);
    const int slotb = (po >> 3) & 3;
    const int rowb7 = wm * 64 + ls * 4;
#pragma unroll
    for (int i = 0; i < 4; ++i) {
#pragma unroll
      for (int r = 0; r < 4; ++r) {
        const int r7 = rowb7 + i * 16 + r;
        const int row = row0 + r7;
        const bool useb0 = ((unsigned)row / 1000u) == b0;
        float v = acc[i][0][r] + (useb0 ? rc0[0] : rc1[0]);
        v = fmaxf(v, acc[i][1][r] + (useb0 ? rc0[1] : rc1[1]));
        v = fmaxf(v, acc[i][2][r] + (useb0 ? rc0[2] : rc1[2]));
        v = fmaxf(v, acc[i][3][r] + (useb0 ? rc0[3] : rc1[3]));
        const int sw = (r7 >> 1) & 3;
        size_t addr = addrBase + r7 * 32 + ((slotb ^ sw) << 3);
        unsigned short hh, ll;
        split2(v, hh, ll);
        Couth[addr] = hh;
        Coutl[addr] = ll;
      }
    }
  } else {
    const int colb = n0 + wn * 64 + lr;
    const int rowb7 = wm * 64 + ls * 4;
    const int pmine = lane & 3;
    float w12j[4], addj[4];
#pragma unroll
    for (int j = 0; j < 4; ++j) {
      const int col = colb + j * 16;
      w12j[j] = (col < 800) ? W12[pmine * 400 + 200 + (col >> 2)] : 0.f;
      addj[j] = (col < 800) ? addv[col] : 0.f;
    }
    const int slice = np * 2 + wn;
#pragma unroll
    for (int i = 0; i < 4; ++i) {
#pragma unroll
      for (int r = 0; r < 4; ++r) {
        const int row = row0 + rowb7 + i * 16 + r;
        float sp = 0.f;
#pragma unroll
        for (int j = 0; j < 4; ++j) {
          float v = acc[i][j][r] + addj[j];
          v = fmaxf(v, __shfl_xor(v, 1));
          v = fmaxf(v, __shfl_xor(v, 2));
          sp = fmaf(v, w12j[j], sp);
        }
        sp += __shfl_xor(sp, 4);
        sp += __shfl_xor(sp, 8);
        if (lr < 4)
          partial[((size_t)row * 14 + slice) * 4 + lr] = sp;
      }
    }
  }
}

// ---------------------------------------------------------------- alpha: m1.W12 + slices + b12 (direct-read, 1 thread = 1 row)
__global__ __launch_bounds__(256) void k_alphad(
    const unsigned short* __restrict__ m1h, const unsigned short* __restrict__ m1l,
    const float* __restrict__ partial, const float* __restrict__ W12,
    const float* __restrict__ b12, float* __restrict__ alpha) {
  __shared__ float w12s[896];
  const int t = threadIdx.x;
  for (int i = t; i < 896; i += 256) {
    int p = i / 224, k = i - p * 224;
    w12s[i] = (k < 200) ? W12[p * 400 + k] : 0.f;
  }
  __syncthreads();
  const int row = blockIdx.x * 256 + t;
  const int rp = row >> 7, r7 = row & 127;
  const int sw = (r7 >> 1) & 3;
  const size_t panelC = (size_t)rp * (size_t)(128 * KB);
  float4 bb = *(const float4*)b12;
  float a0 = bb.x, a1 = bb.y, a2 = bb.z, a3 = bb.w;
#pragma unroll
  for (int kt = 0; kt < 7; ++kt) {
    const size_t tb = panelC + (size_t)kt * 4096 + r7 * 32;
#pragma unroll
    for (int c = 0; c < 4; ++c) {
      const short8 hv = *(const short8*)(m1h + tb + ((c ^ sw) << 3));
      const short8 lv = *(const short8*)(m1l + tb + ((c ^ sw) << 3));
      const int kb = kt * 32 + c * 8;
#pragma unroll
      for (int e = 0; e < 8; ++e) {
        float val = bf2f((unsigned short)hv[e]) + bf2f((unsigned short)lv[e]);
        a0 = fmaf(val, w12s[kb + e], a0);
        a1 = fmaf(val, w12s[224 + kb + e], a1);
        a2 = fmaf(val, w12s[448 + kb + e], a2);
        a3 = fmaf(val, w12s[672 + kb + e], a3);
      }
    }
  }
  const float4* pr = (const float4*)(partial + (size_t)row * 56);
#pragma unroll
  for (int s = 0; s < 14; ++s) {
    float4 p4 = pr[s];
    a0 += p4.x; a1 += p4.y; a2 += p4.z; a3 += p4.w;
  }
  alpha[row] = fmaxf(fmaxf(a0, a1), fmaxf(a2, a3));
}

// ---------------------------------------------------------------- argmax + logsumexp (alpha input)
__global__ __launch_bounds__(256) void k_argmax(const float* __restrict__ alpha,
    const int* __restrict__ dmask, const int* __restrict__ span, int tag,
    int* __restrict__ idx_out, float* __restrict__ atgt_out) {
  int b = blockIdx.x, t = threadIdx.x;
  __shared__ float vals[MM];
  __shared__ float rv[256];
  __shared__ int ri[256];
  float bestv = -3.4e38f; int besti = 0x7fffffff;
  for (int m = t; m < MM; m += 256) {
    float v = alpha[b * MM + m];
    if (!dmask[b * MM + m]) v += NEGV;
    vals[m] = v;
    if (v > bestv || (v == bestv && m < besti)) { bestv = v; besti = m; }
  }
  rv[t] = bestv; ri[t] = besti; __syncthreads();
  for (int s = 128; s > 0; s >>= 1) {
    if (t < s) {
      float v2 = rv[t + s]; int i2 = ri[t + s];
      if (v2 > rv[t] || (v2 == rv[t] && i2 < ri[t])) { rv[t] = v2; ri[t] = i2; }
    }
    __syncthreads();
  }
  float vmax = rv[0]; int vidx = ri[0];
  __syncthreads();
  float se = 0.f;
  for (int m = t; m < MM; m += 256) se += expf(vals[m] - vmax);
  rv[t] = se; __syncthreads();
  for (int s = 128; s > 0; s >>= 1) { if (t < s) rv[t] += rv[t + s]; __syncthreads(); }
  if (t == 0) {
    int tgt = span[b * 2 + tag];
    atgt_out[b] = vals[tgt] - vmax - logf(rv[0]);
    idx_out[b] = vidx;
  }
}

// ================= fallback GEMM + reduce =================
template <int MODE, int PRESPLIT>
__global__ __launch_bounds__(256) void k_mgemm(
    const float* __restrict__ Af, int lda, int KsrcA,
    const unsigned short* __restrict__ Ah, const unsigned short* __restrict__ Al,
    const unsigned short* __restrict__ Bh, const unsigned short* __restrict__ Bl, int Kpad,
    const float* __restrict__ addv,
    unsigned short* __restrict__ Couth, unsigned short* __restrict__ Coutl,
    float* __restrict__ partial, const float* __restrict__ W12, int slice_base) {
  __shared__ unsigned short sAh[128 * LSTR], sAl[128 * LSTR];
  __shared__ unsigned short sBh[128 * LSTR], sBl[128 * LSTR];
  const int tid = threadIdx.x;
  const int lane = tid & 63, wave = tid >> 6;
  const int wm = wave >> 1, wn = wave & 1;
  const int n0 = blockIdx.x * 128, row0 = blockIdx.y * 128;
  const int lr = lane & 15, ls = lane >> 4;
  f32x4 acc[4][4];
#pragma unroll
  for (int i = 0; i < 4; ++i)
#pragma unroll
    for (int j = 0; j < 4; ++j) acc[i][j] = (f32x4){0.f, 0.f, 0.f, 0.f};
  const int srow = tid >> 1, shalf = tid & 1;
  const float* Afp = Af ? (Af + (size_t)(row0 + srow) * lda + shalf * 16) : nullptr;
  const unsigned short* Ahp = Ah ? (Ah + (size_t)(row0 + srow) * Kpad + shalf * 16) : nullptr;
  const unsigned short* Alp = Al ? (Al + (size_t)(row0 + srow) * Kpad + shalf * 16) : nullptr;
  const unsigned short* Bhp = Bh + (size_t)(n0 + srow) * Kpad + shalf * 16;
  const unsigned short* Blp = Bl + (size_t)(n0 + srow) * Kpad + shalf * 16;
  const int wo = srow * LSTR + shalf * 16;
  const int aoff = (wm * 64 + lr) * LSTR + ls * 8;
  const int boff = (wn * 64 + lr) * LSTR + ls * 8;
  short8 rah0, rah1, ral0, ral1, rbh0, rbh1, rbl0, rbl1;
  auto loadk = [&](int kt) {
    if (PRESPLIT) {
      rah0 = *(const short8*)(Ahp + kt * 32);
      rah1 = *(const short8*)(Ahp + kt * 32 + 8);
      ral0 = *(const short8*)(Alp + kt * 32);
      ral1 = *(const short8*)(Alp + kt * 32 + 8);
    } else {
      const int kk = kt * 32 + shalf * 16;
      float av[16];
#pragma unroll
      for (int q = 0; q < 4; ++q) {
        float4 v;
        if (kk + q * 4 + 4 <= KsrcA) v = *(const float4*)(Afp + kt * 32 + q * 4);
        else v = make_float4(0.f, 0.f, 0.f, 0.f);
        av[q * 4 + 0] = v.x; av[q * 4 + 1] = v.y;
        av[q * 4 + 2] = v.z; av[q * 4 + 3] = v.w;
      }
#pragma unroll
      for (int e = 0; e < 8; ++e) {
        unsigned short hh, ll;
        split2(av[e], hh, ll);     rah0[e] = (short)hh; ral0[e] = (short)ll;
        split2(av[8 + e], hh, ll); rah1[e] = (short)hh; ral1[e] = (short)ll;
      }
    }
    rbh0 = *(const short8*)(Bhp + kt * 32);
    rbh1 = *(const short8*)(Bhp + kt * 32 + 8);
    rbl0 = *(const short8*)(Blp + kt * 32);
    rbl1 = *(const short8*)(Blp + kt * 32 + 8);
  };
  const int nk = Kpad >> 5;
  loadk(0);
  for (int kt = 0; kt < nk; ++kt) {
    *(short8*)&sAh[wo] = rah0; *(short8*)&sAh[wo + 8] = rah1;
    *(short8*)&sAl[wo] = ral0; *(short8*)&sAl[wo + 8] = ral1;
    *(short8*)&sBh[wo] = rbh0; *(short8*)&sBh[wo + 8] = rbh1;
    *(short8*)&sBl[wo] = rbl0; *(short8*)&sBl[wo + 8] = rbl1;
    __syncthreads();
    if (kt + 1 < nk) loadk(kt + 1);
    short8 fa[4], fb[4];
#pragma unroll
    for (int i = 0; i < 4; ++i) fa[i] = *(const short8*)&sAh[aoff + i * 16 * LSTR];
#pragma unroll
    for (int j = 0; j < 4; ++j) fb[j] = *(const short8*)&sBh[boff + j * 16 * LSTR];
#pragma unroll
    for (int i = 0; i < 4; ++i)
#pragma unroll
      for (int j = 0; j < 4; ++j)
        acc[i][j] = __builtin_amdgcn_mfma_f32_16x16x32_bf16(fa[i], fb[j], acc[i][j], 0, 0, 0);
    short8 fc[4];
#pragma unroll
    for (int j = 0; j < 4; ++j) fc[j] = *(const short8*)&sBl[boff + j * 16 * LSTR];
#pragma unroll
    for (int i = 0; i < 4; ++i)
#pragma unroll
      for (int j = 0; j < 4; ++j)
        acc[i][j] = __builtin_amdgcn_mfma_f32_16x16x32_bf16(fa[i], fc[j], acc[i][j], 0, 0, 0);
#pragma unroll
    for (int i = 0; i < 4; ++i) fa[i] = *(const short8*)&sAl[aoff + i * 16 * LSTR];
#pragma unroll
    for (int i = 0; i < 4; ++i)
#pragma unroll
      for (int j = 0; j < 4; ++j)
        acc[i][j] = __builtin_amdgcn_mfma_f32_16x16x32_bf16(fa[i], fb[j], acc[i][j], 0, 0, 0);
    __syncthreads();
  }
  const int colb = n0 + wn * 64 + lr;
  const int rowb = row0 + wm * 64 + ls * 4;
  const int pmine = lane & 3;
  const int woff = (MODE == 0) ? 0 : 200;
  float w12j[4], addj[4];
#pragma unroll
  for (int j = 0; j < 4; ++j) {
    const int col = colb + j * 16;
    w12j[j] = (col < 800) ? W12[pmine * 400 + woff + (col >> 2)] : 0.f;
    if (MODE == 1) addj[j] = (col < 800) ? addv[col] : 0.f;
  }
  const int slice = slice_base + blockIdx.x * 2 + wn;
#pragma unroll
  for (int i = 0; i < 4; ++i) {
#pragma unroll
    for (int r = 0; r < 4; ++r) {
      const int row = rowb + i * 16 + r;
      float sp = 0.f;
#pragma unroll
      for (int j = 0; j < 4; ++j) {
        const int col = colb + j * 16;
        float v = acc[i][j][r];
        if (MODE == 0) {
          const unsigned bidx = (unsigned)row / 1000u;
          v += addv[bidx * NPAD + col];
        } else {
          v += addj[j];
        }
        v = fmaxf(v, __shfl_xor(v, 1));
        v = fmaxf(v, __shfl_xor(v, 2));
        if (MODE == 0 && (lane & 3) == 0) {
          unsigned short hh, ll;
          split2(v, hh, ll);
          Couth[(size_t)row * KB + (col >> 2)] = hh;
          Coutl[(size_t)row * KB + (col >> 2)] = ll;
        }
        sp = fmaf(v, w12j[j], sp);
      }
      sp += __shfl_xor(sp, 4);
      sp += __shfl_xor(sp, 8);
      if (lr < 4)
        partial[((size_t)row * NSLICE + slice) * 4 + lr] = sp;
    }
  }
}

__global__ __launch_bounds__(256) void k_reduce(const float* __restrict__ partial,
    const float* __restrict__ b12, const int* __restrict__ dmask,
    const int* __restrict__ span, int tag,
    int* __restrict__ idx_out, float* __restrict__ atgt_out) {
  int b = blockIdx.x, t = threadIdx.x;
  __shared__ float vals[MM];
  __shared__ float rv[256];
  __shared__ int ri[256];
  float4 bb = *(const float4*)b12;
  float bestv = -3.4e38f; int besti = 0x7fffffff;
  for (int m = t; m < MM; m += 256) {
    const float4* pr = (const float4*)(partial + ((size_t)(b * MM + m)) * (NSLICE * 4));
    float4 a4 = bb;
#pragma unroll
    for (int s = 0; s < NSLICE; ++s) {
      float4 p4 = pr[s];
      a4.x += p4.x; a4.y += p4.y; a4.z += p4.z; a4.w += p4.w;
    }
    float v = fmaxf(fmaxf(a4.x, a4.y), fmaxf(a4.z, a4.w));
    if (!dmask[b * MM + m]) v += NEGV;
    vals[m] = v;
    if (v > bestv || (v == bestv && m < besti)) { bestv = v; besti = m; }
  }
  rv[t] = bestv; ri[t] = besti; __syncthreads();
  for (int s = 128; s > 0; s >>= 1) {
    if (t < s) {
      float v2 = rv[t + s]; int i2 = ri[t + s];
      if (v2 > rv[t] || (v2 == rv[t] && i2 < ri[t])) { rv[t] = v2; ri[t] = i2; }
    }
    __syncthreads();
  }
  float vmax = rv[0]; int vidx = ri[0];
  __syncthreads();
  float se = 0.f;
  for (int m = t; m < MM; m += 256) se += expf(vals[m] - vmax);
  rv[t] = se; __syncthreads();
  for (int s = 128; s > 0; s >>= 1) { if (t < s) rv[t] += rv[t + s]; __syncthreads(); }
  if (t == 0) {
    int tgt = span[b * 2 + tag];
    atgt_out[b] = vals[tgt] - vmax - logf(rv[0]);
    idx_out[b] = vidx;
  }
}

// ---------------------------------------------------------------- state update + loss
__global__ __launch_bounds__(64) void k_update(const int* __restrict__ idx_buf,
    const float* __restrict__ atgt, int* __restrict__ st, int* __restrict__ mstate,
    float* __restrict__ pout, float* __restrict__ loss, int first) {
  int b = threadIdx.x;
  int idx = idx_buf[b];
  int sold = st[b], msold = mstate[b];
  int snew = first ? idx : (msold ? idx : 0);
  int msnew = first ? 1 : ((snew != (msold ? sold : 0)) ? 1 : 0);
  st[b] = snew; mstate[b] = msnew;
  if (msnew) pout[b] = (float)snew;
  float asum = atgt[b];
  float csum = (float)msnew;
  for (int off = 32; off > 0; off >>= 1) {
    asum += __shfl_down(asum, off);
    csum += __shfl_down(csum, off);
  }
  if (b == 0) loss[0] += (-asum / (float)BB) * csum / (float)(BB * TT);
}

// ---------------------------------------------------------------- launch
extern "C" void kernel_launch(void* const* d_in, const int* in_sizes, int n_in,
                              void* d_out, int out_size, void* d_ws, size_t ws_size,
                              hipStream_t stream) {
  const float* U     = (const float*)d_in[0];
  const int*   dmask = (const int*)d_in[1];
  const int*   span  = (const int*)d_in[2];
  const float* w_ih  = (const float*)d_in[3];
  const float* w_hh  = (const float*)d_in[4];
  const float* b_ih  = (const float*)d_in[5];
  const float* b_hh  = (const float*)d_in[6];
  const float* Wr[2]  = {(const float*)d_in[7],  (const float*)d_in[14]};
  const float* W1[2]  = {(const float*)d_in[8],  (const float*)d_in[15]};
  const float* b1[2]  = {(const float*)d_in[9],  (const float*)d_in[16]};
  const float* W2[2]  = {(const float*)d_in[10], (const float*)d_in[17]};
  const float* b2[2]  = {(const float*)d_in[11], (const float*)d_in[18]};
  const float* W12[2] = {(const float*)d_in[12], (const float*)d_in[19]};
  const float* b12[2] = {(const float*)d_in[13], (const float*)d_in[20]};
  float* out = (float*)d_out;

  size_t off = 0;
  char* base = (char*)d_ws;
  auto alloc = [&](size_t n) {
    void* p = base + off;
    off += (n + 255) & ~(size_t)255;
    return p;
  };
  float* rcorr = (float*)alloc((size_t)BB * NPAD * 4);
  float* ue    = (float*)alloc((size_t)BB * 400 * 4);
  float* ucat  = (float*)alloc((size_t)BB * 800 * 4);
  float* gbuf  = (float*)alloc((size_t)BB * 800 * 4);
  float* rbuf  = (float*)alloc((size_t)BB * 200 * 4);
  float* hbuf  = (float*)alloc((size_t)BB * H * 4);
  float* cbuf  = (float*)alloc((size_t)BB * H * 4);
  float* alphab = (float*)alloc((size_t)ROWS * 4);
  float* atgt  = (float*)alloc((size_t)BB * 4);
  int* st_s = (int*)alloc(BB * 4);
  int* st_e = (int*)alloc(BB * 4);
  int* msb  = (int*)alloc(BB * 4);
  int* meb  = (int*)alloc(BB * 4);
  int* idxb = (int*)alloc(BB * 4);
  unsigned short *W1h[2], *W1l[2], *W2h[2], *W2l[2];
  for (int g = 0; g < 2; ++g) {
    W1h[g] = (unsigned short*)alloc((size_t)NPAD * KA * 2);
    W1l[g] = (unsigned short*)alloc((size_t)NPAD * KA * 2);
    W2h[g] = (unsigned short*)alloc((size_t)NPAD * KB * 2);
    W2l[g] = (unsigned short*)alloc((size_t)NPAD * KB * 2);
  }
  unsigned short* m1h = (unsigned short*)alloc((size_t)ROWS * KB * 2);
  unsigned short* m1l = (unsigned short*)alloc((size_t)ROWS * KB * 2);

  const size_t P14_B  = (size_t)ROWS * 14 * 4 * 4;
  const size_t TIH_B  = (size_t)800 * 800 * 4;
  const size_t THH_B  = (size_t)200 * 800 * 4;
  const size_t TWR_B  = (size_t)1000 * 200 * 4;
  const size_t TW1_B  = (size_t)200 * 800 * 4;
  const size_t UHL_B  = (size_t)ROWS * KA * 2;
  size_t panel_need = off + P14_B + TIH_B + THH_B + 2 * TWR_B + 2 * TW1_B + 2 * UHL_B + 4096;
  bool panelPath = (ws_size >= panel_need);

  if (panelPath) {
    float* partial = (float*)alloc(P14_B);
    float* wTih = (float*)alloc(TIH_B);
    float* wThh = (float*)alloc(THH_B);
    float* WrT[2]  = {(float*)alloc(TWR_B), (float*)alloc(TWR_B)};
    float* W1cT[2] = {(float*)alloc(TW1_B), (float*)alloc(TW1_B)};
    unsigned short* Uh = (unsigned short*)alloc(UHL_B);
    unsigned short* Ul = (unsigned short*)alloc(UHL_B);

    k_init<<<BB, 256, 0, stream>>>(dmask, st_s, st_e, msb, meb, hbuf, cbuf, out);
    for (int g = 0; g < 2; ++g) {
      k_splitPW1<<<NPAD, 256, 0, stream>>>(W1[g], W1h[g], W1l[g]);
      k_splitP<<<NPAD, 256, 0, stream>>>(W2[g], 200, 200, 800, W2h[g], W2l[g], KB);
      k_T<<<1000, 256, 0, stream>>>(Wr[g], 1000, 200, 0, WrT[g]);
      k_T<<<200, 256, 0, stream>>>(W1[g], 600, 800, 400, W1cT[g]);
    }
    k_T<<<800, 256, 0, stream>>>(w_ih, 800, 800, 0, wTih);
    k_T<<<200, 256, 0, stream>>>(w_hh, 200, 800, 0, wThh);
    k_splitP<<<ROWS, 256, 0, stream>>>(U, 400, 400, ROWS, Uh, Ul, KA);

    dim3 g13(13, BB), g4(4, BB), g14(14, BB);
    for (int t = 0; t < TT; ++t) {
      int first = (t == 0) ? 1 : 0;
      // ---- tag s ----
      k_prep<<<BB, 256, 0, stream>>>(U, st_s, st_e, ucat, ue);
      k_gates<<<g13, 256, 0, stream>>>(ucat, hbuf, wTih, wThh, b_ih, b_hh, gbuf);
      k_act<<<BB, 256, 0, stream>>>(gbuf, hbuf, cbuf);
      k_r2<0><<<g4, 256, 0, stream>>>(U, st_s, ucat, ue, hbuf, WrT[0], rbuf);
      k_rcorr<<<g14, 256, 0, stream>>>(rbuf, W1cT[0], b1[0], rcorr);
      k_pgemm<0><<<GG, 256, 0, stream>>>(Uh, Ul, W1h[0], W1l[0],
          rcorr, m1h, m1l, nullptr, nullptr);
      k_pgemm<1><<<GG, 256, 0, stream>>>(m1h, m1l, W2h[0], W2l[0],
          b2[0], nullptr, nullptr, partial, W12[0]);
      k_alphad<<<ROWS / 256, 256, 0, stream>>>(m1h, m1l, partial, W12[0], b12[0], alphab);
      k_argmax<<<BB, 256, 0, stream>>>(alphab, dmask, span, 0, idxb, atgt);
      k_update<<<1, 64, 0, stream>>>(idxb, atgt, st_s, msb, out + 1, out, first);
      // ---- tag e ----
      k_r2<1><<<g4, 256, 0, stream>>>(U, st_s, ucat, ue, hbuf, WrT[1], rbuf);
      k_rcorr<<<g14, 256, 0, stream>>>(rbuf, W1cT[1], b1[1], rcorr);
      k_pgemm<0><<<GG, 256, 0, stream>>>(Uh, Ul, W1h[1], W1l[1],
          rcorr, m1h, m1l, nullptr, nullptr);
      k_pgemm<1><<<GG, 256, 0, stream>>>(m1h, m1l, W2h[1], W2l[1],
          b2[1], nullptr, nullptr, partial, W12[1]);
      k_alphad<<<ROWS / 256, 256, 0, stream>>>(m1h, m1l, partial, W12[1], b12[1], alphab);
      k_argmax<<<BB, 256, 0, stream>>>(alphab, dmask, span, 1, idxb, atgt);
      k_update<<<1, 64, 0, stream>>>(idxb, atgt, st_e, meb, out + 1 + BB, out, first);
    }
  } else {
    // fallback: round-7 path
    float* partial = (float*)alloc((size_t)ROWS * NSLICE * 4 * 4);
    k_init<<<BB, 256, 0, stream>>>(dmask, st_s, st_e, msb, meb, hbuf, cbuf, out);
    for (int g = 0; g < 2; ++g) {
      k_split<<<NPAD, 256, 0, stream>>>(W1[g], 600, 400, 800, W1h[g], W1l[g], KA);
      k_split<<<NPAD, 256, 0, stream>>>(W2[g], 200, 200, 800, W2h[g], W2l[g], KB);
    }
    dim3 gg(NPAD / 128, ROWS / 128);
    for (int t = 0; t < TT; ++t) {
      int first = (t == 0) ? 1 : 0;
      for (int tag = 0; tag < 2; ++tag) {
        if (tag == 0)
          k_lstm_r<<<BB, 1024, 0, stream>>>(U, st_s, st_e, hbuf, cbuf, w_ih, w_hh, b_ih, b_hh,
                                            Wr[0], W1[0], b1[0], rcorr, ue);
        else
          k_re<<<BB, 1024, 0, stream>>>(U, st_s, ue, hbuf, Wr[1], W1[1], b1[1], rcorr);

        k_mgemm<0, 0><<<gg, 256, 0, stream>>>(U, 400, 400, nullptr, nullptr,
            W1h[tag], W1l[tag], KA, rcorr, m1h, m1l, partial, W12[tag], 0);
        k_mgemm<1, 1><<<gg, 256, 0, stream>>>(nullptr, 0, 0, m1h, m1l,
            W2h[tag], W2l[tag], KB, b2[tag], nullptr, nullptr, partial, W12[tag], 14);

        k_reduce<<<BB, 256, 0, stream>>>(partial, b12[tag], dmask, span, tag, idxb, atgt);
        if (tag == 0)
          k_update<<<1, 64, 0, stream>>>(idxb, atgt, st_s, msb, out + 1, out, first);
        else
          k_update<<<1, 64, 0, stream>>>(idxb, atgt, st_e, meb, out + 1 + BB, out, first);
      }
    }
  }
}